// Round 1
// baseline (15150.546 us; speedup 1.0000x reference)
//
#include <hip/hip_runtime.h>

typedef unsigned short u16;
typedef short bf16x8 __attribute__((ext_vector_type(8)));
typedef unsigned short ushort8 __attribute__((ext_vector_type(8)));
typedef float f32x4 __attribute__((ext_vector_type(4)));

#define DEVI __device__ __forceinline__

enum { BB = 4, TT = 512, HH = 1024, VV = 32000, H4 = 4096 };

DEVI u16 f2bf(float f) {
    union { float f; unsigned u; } x; x.f = f;
    unsigned r = x.u + 0x7fff + ((x.u >> 16) & 1);
    return (u16)(r >> 16);
}
DEVI float bf2f(u16 u) {
    union { unsigned u; float f; } x; x.u = ((unsigned)u) << 16;
    return x.f;
}

// ---------------- transpose + cast: src [R][C] f32 -> dst [C][R] bf16 ----------------
__global__ void transpose_cast(const float* __restrict__ src, u16* __restrict__ dst, int R, int C) {
    __shared__ float tile[32][33];
    int c0 = blockIdx.x * 32, r0 = blockIdx.y * 32;
    int x = threadIdx.x, y = threadIdx.y;
#pragma unroll
    for (int i = 0; i < 32; i += 8) tile[y + i][x] = src[(size_t)(r0 + y + i) * C + c0 + x];
    __syncthreads();
#pragma unroll
    for (int i = 0; i < 32; i += 8) dst[(size_t)(c0 + y + i) * R + r0 + x] = f2bf(tile[x][y + i]);
}

__global__ void cast_bf16(const float* __restrict__ src, u16* __restrict__ dst, int n) {
    int i = blockIdx.x * 256 + threadIdx.x;
    if (i < n) dst[i] = f2bf(src[i]);
}

__global__ void zero_buf(float* p, int n) {
    int i = blockIdx.x * 256 + threadIdx.x;
    if (i < n) p[i] = 0.f;
}

// ---------------- gather + layernorm (layer 0 input) ----------------
__global__ __launch_bounds__(256) void gather_ln(const int* __restrict__ x, const float* __restrict__ emb,
                                                 const float* __restrict__ g, const float* __restrict__ b,
                                                 float* __restrict__ xe, u16* __restrict__ xn0) {
    int t = blockIdx.x, bb = blockIdx.y;
    int row = x[bb * TT + t];
    const float* e = emb + (size_t)row * HH;
    float v[4]; float s = 0.f, s2 = 0.f;
#pragma unroll
    for (int p = 0; p < 4; p++) { v[p] = e[p * 256 + threadIdx.x]; s += v[p]; s2 += v[p] * v[p]; }
    __shared__ float ls[4], ls2[4];
    for (int off = 32; off; off >>= 1) { s += __shfl_xor(s, off); s2 += __shfl_xor(s2, off); }
    int w = threadIdx.x >> 6, lane = threadIdx.x & 63;
    if (lane == 0) { ls[w] = s; ls2[w] = s2; }
    __syncthreads();
    s = ls[0] + ls[1] + ls[2] + ls[3];
    s2 = ls2[0] + ls2[1] + ls2[2] + ls2[3];
    float mu = s * (1.f / HH);
    float var = s2 * (1.f / HH) - mu * mu;
    float rs = rsqrtf(var + 1e-6f);
    size_t base = ((size_t)t * BB + bb) * HH;
#pragma unroll
    for (int p = 0; p < 4; p++) {
        int j = p * 256 + threadIdx.x;
        xe[base + j] = v[p];
        xn0[base + j] = f2bf((v[p] - mu) * rs * g[j] + b[j]);
    }
}

// ---------------- layernorm of 4 rows (per-step, layer 1 input) ----------------
__global__ __launch_bounds__(256) void ln_rows(const float* __restrict__ in, const float* __restrict__ g,
                                               const float* __restrict__ b, u16* __restrict__ outbf) {
    int bb = blockIdx.x;
    const float* e = in + (size_t)bb * HH;
    float v[4]; float s = 0.f, s2 = 0.f;
#pragma unroll
    for (int p = 0; p < 4; p++) { v[p] = e[p * 256 + threadIdx.x]; s += v[p]; s2 += v[p] * v[p]; }
    __shared__ float ls[4], ls2[4];
    for (int off = 32; off; off >>= 1) { s += __shfl_xor(s, off); s2 += __shfl_xor(s2, off); }
    int w = threadIdx.x >> 6, lane = threadIdx.x & 63;
    if (lane == 0) { ls[w] = s; ls2[w] = s2; }
    __syncthreads();
    s = ls[0] + ls[1] + ls[2] + ls[3];
    s2 = ls2[0] + ls2[1] + ls2[2] + ls2[3];
    float mu = s * (1.f / HH);
    float var = s2 * (1.f / HH) - mu * mu;
    float rs = rsqrtf(var + 1e-6f);
#pragma unroll
    for (int p = 0; p < 4; p++) {
        int j = p * 256 + threadIdx.x;
        outbf[bb * HH + j] = f2bf((v[p] - mu) * rs * g[j] + b[j]);
    }
}

// ---------------- MFMA GEMM: C[M,N] = A[M,K](bf16) * Bt[N,K](bf16)^T ----------------
// MODE 0: Cf = v + bias[col]          (f32 store)
// MODE 1: Cb = bf16(relu(v+bias))     (bf16 store)
// MODE 2: Cf += v                     (accumulate)
// MODE 3: logits: row m=t*B+b -> out[b*T*V + t*V + col] = v
template <int MODE>
__global__ __launch_bounds__(256) void gemm_bt(const u16* __restrict__ A, const u16* __restrict__ Bt,
                                               float* __restrict__ Cf, u16* __restrict__ Cb,
                                               const float* __restrict__ bias, int M, int N, int K) {
    __shared__ u16 ldsA[128 * 40];
    __shared__ u16 ldsB[128 * 40];
    const int tid = threadIdx.x;
    const int m0 = blockIdx.y * 128, n0 = blockIdx.x * 128;
    const int lane = tid & 63, wid = tid >> 6;
    const int wr = wid >> 1, wc = wid & 1;
    const int l15 = lane & 15, lk = (lane >> 4) * 8;
    f32x4 acc[4][4];
#pragma unroll
    for (int a = 0; a < 4; a++)
#pragma unroll
        for (int b = 0; b < 4; b++) { f32x4 z = {0.f, 0.f, 0.f, 0.f}; acc[a][b] = z; }

    const int arow = tid >> 2, acol = (tid & 3) * 8;
    for (int k0 = 0; k0 < K; k0 += 32) {
#pragma unroll
        for (int p = 0; p < 2; p++) {
            int r = arow + p * 64;
            ushort8 va = *(const ushort8*)(A + (size_t)(m0 + r) * K + k0 + acol);
            *(ushort8*)&ldsA[r * 40 + acol] = va;
            ushort8 vb = *(const ushort8*)(Bt + (size_t)(n0 + r) * K + k0 + acol);
            *(ushort8*)&ldsB[r * 40 + acol] = vb;
        }
        __syncthreads();
        bf16x8 af[4], bfr[4];
#pragma unroll
        for (int mi = 0; mi < 4; mi++) af[mi] = *(const bf16x8*)&ldsA[(wr * 64 + mi * 16 + l15) * 40 + lk];
#pragma unroll
        for (int ni = 0; ni < 4; ni++) bfr[ni] = *(const bf16x8*)&ldsB[(wc * 64 + ni * 16 + l15) * 40 + lk];
#pragma unroll
        for (int mi = 0; mi < 4; mi++)
#pragma unroll
            for (int ni = 0; ni < 4; ni++)
                acc[mi][ni] = __builtin_amdgcn_mfma_f32_16x16x32_bf16(af[mi], bfr[ni], acc[mi][ni], 0, 0, 0);
        __syncthreads();
    }
#pragma unroll
    for (int mi = 0; mi < 4; mi++) {
#pragma unroll
        for (int ni = 0; ni < 4; ni++) {
#pragma unroll
            for (int r = 0; r < 4; r++) {
                int gr = m0 + wr * 64 + mi * 16 + (lane >> 4) * 4 + r;
                int gc = n0 + wc * 64 + ni * 16 + l15;
                float v = acc[mi][ni][r];
                if (MODE == 0) {
                    Cf[(size_t)gr * N + gc] = v + bias[gc];
                } else if (MODE == 1) {
                    float u = v + bias[gc];
                    Cb[(size_t)gr * N + gc] = f2bf(u > 0.f ? u : 0.f);
                } else if (MODE == 2) {
                    Cf[(size_t)gr * N + gc] += v;
                } else {
                    int b = gr & 3, t = gr >> 2;
                    Cf[((size_t)b * TT + t) * VV + gc] = v;
                }
            }
        }
    }
}

// ---------------- sequential step kernels ----------------
// Layer 0 gates: z = pre_z0[t] + h_prev @ WlhT ; update c, h
__global__ __launch_bounds__(256) void lstm0_step(const u16* __restrict__ WlhT, const float* __restrict__ pz,
                                                  const float* __restrict__ h_prev, float* __restrict__ h_new,
                                                  float* __restrict__ c) {
    int lane = threadIdx.x & 63, w = threadIdx.x >> 6;
    int i = blockIdx.x * 4 + w;
    float acc[4][4];
#pragma unroll
    for (int g = 0; g < 4; g++)
#pragma unroll
        for (int b = 0; b < 4; b++) acc[g][b] = 0.f;
#pragma unroll
    for (int ch = 0; ch < 2; ch++) {
        int k = ch * 512 + lane * 8;
        float hv[4][8];
#pragma unroll
        for (int b = 0; b < 4; b++) {
            *(f32x4*)&hv[b][0] = *(const f32x4*)&h_prev[b * HH + k];
            *(f32x4*)&hv[b][4] = *(const f32x4*)&h_prev[b * HH + k + 4];
        }
#pragma unroll
        for (int g = 0; g < 4; g++) {
            ushort8 wv = *(const ushort8*)&WlhT[(size_t)((g << 10) + i) * HH + k];
#pragma unroll
            for (int j = 0; j < 8; j++) {
                float wf = bf2f(wv[j]);
#pragma unroll
                for (int b = 0; b < 4; b++) acc[g][b] += wf * hv[b][j];
            }
        }
    }
#pragma unroll
    for (int g = 0; g < 4; g++)
#pragma unroll
        for (int b = 0; b < 4; b++)
            for (int off = 32; off; off >>= 1) acc[g][b] += __shfl_xor(acc[g][b], off);
    if (lane == 0) {
#pragma unroll
        for (int b = 0; b < 4; b++) {
            float zi = acc[0][b] + pz[b * H4 + i];
            float zf = acc[1][b] + pz[b * H4 + 1024 + i];
            float zo = acc[2][b] + pz[b * H4 + 2048 + i];
            float zg = acc[3][b] + pz[b * H4 + 3072 + i];
            float ig = 1.f / (1.f + expf(-zi));
            float fg = 1.f / (1.f + expf(-zf));
            float og = 1.f / (1.f + expf(-zo));
            float cc = fg * c[b * HH + i] + ig * tanhf(zg);
            c[b * HH + i] = cc;
            h_new[b * HH + i] = og * tanhf(cc);
        }
    }
}

// y0 = xe + ff0 + h0 @ Wo0T + bo0
__global__ __launch_bounds__(256) void y0_step(const u16* __restrict__ WoT, const float* __restrict__ h,
                                               const float* __restrict__ xe_t, const float* __restrict__ ff_t,
                                               const float* __restrict__ bo0, float* __restrict__ y_t) {
    int lane = threadIdx.x & 63, w = threadIdx.x >> 6;
    int j = blockIdx.x * 4 + w;
    float acc[4] = {0.f, 0.f, 0.f, 0.f};
#pragma unroll
    for (int ch = 0; ch < 2; ch++) {
        int k = ch * 512 + lane * 8;
        float hv[4][8];
#pragma unroll
        for (int b = 0; b < 4; b++) {
            *(f32x4*)&hv[b][0] = *(const f32x4*)&h[b * HH + k];
            *(f32x4*)&hv[b][4] = *(const f32x4*)&h[b * HH + k + 4];
        }
        ushort8 wv = *(const ushort8*)&WoT[(size_t)j * HH + k];
#pragma unroll
        for (int jj = 0; jj < 8; jj++) {
            float wf = bf2f(wv[jj]);
#pragma unroll
            for (int b = 0; b < 4; b++) acc[b] += wf * hv[b][jj];
        }
    }
#pragma unroll
    for (int b = 0; b < 4; b++)
        for (int off = 32; off; off >>= 1) acc[b] += __shfl_xor(acc[b], off);
    if (lane == 0) {
#pragma unroll
        for (int b = 0; b < 4; b++)
            y_t[b * HH + j] = acc[b] + xe_t[b * HH + j] + ff_t[b * HH + j] + bo0[j];
    }
}

// Layer 1 gates: z = xn1 @ WlxT + h_prev @ WlhT + bl1 ; update c, h; emit bf16 h
__global__ __launch_bounds__(256) void lstm1_step(const u16* __restrict__ WlxT, const u16* __restrict__ WlhT,
                                                  const u16* __restrict__ xn_t, const float* __restrict__ h_prev,
                                                  const float* __restrict__ bl1, float* __restrict__ c,
                                                  float* __restrict__ h_new, u16* __restrict__ hbf_t) {
    int lane = threadIdx.x & 63, w = threadIdx.x >> 6;
    int i = blockIdx.x * 4 + w;
    float acc[4][4];
#pragma unroll
    for (int g = 0; g < 4; g++)
#pragma unroll
        for (int b = 0; b < 4; b++) acc[g][b] = 0.f;
#pragma unroll
    for (int ch = 0; ch < 2; ch++) {
        int k = ch * 512 + lane * 8;
        float hv[4][8], xv[4][8];
#pragma unroll
        for (int b = 0; b < 4; b++) {
            *(f32x4*)&hv[b][0] = *(const f32x4*)&h_prev[b * HH + k];
            *(f32x4*)&hv[b][4] = *(const f32x4*)&h_prev[b * HH + k + 4];
            ushort8 xu = *(const ushort8*)&xn_t[b * HH + k];
#pragma unroll
            for (int j = 0; j < 8; j++) xv[b][j] = bf2f(xu[j]);
        }
#pragma unroll
        for (int g = 0; g < 4; g++) {
            ushort8 wx = *(const ushort8*)&WlxT[(size_t)((g << 10) + i) * HH + k];
            ushort8 wh = *(const ushort8*)&WlhT[(size_t)((g << 10) + i) * HH + k];
#pragma unroll
            for (int j = 0; j < 8; j++) {
                float wxf = bf2f(wx[j]), whf = bf2f(wh[j]);
#pragma unroll
                for (int b = 0; b < 4; b++) acc[g][b] += wxf * xv[b][j] + whf * hv[b][j];
            }
        }
    }
#pragma unroll
    for (int g = 0; g < 4; g++)
#pragma unroll
        for (int b = 0; b < 4; b++)
            for (int off = 32; off; off >>= 1) acc[g][b] += __shfl_xor(acc[g][b], off);
    if (lane == 0) {
#pragma unroll
        for (int b = 0; b < 4; b++) {
            float zi = acc[0][b] + bl1[i];
            float zf = acc[1][b] + bl1[1024 + i];
            float zo = acc[2][b] + bl1[2048 + i];
            float zg = acc[3][b] + bl1[3072 + i];
            float ig = 1.f / (1.f + expf(-zi));
            float fg = 1.f / (1.f + expf(-zf));
            float og = 1.f / (1.f + expf(-zo));
            float cc = fg * c[b * HH + i] + ig * tanhf(zg);
            c[b * HH + i] = cc;
            float hh = og * tanhf(cc);
            h_new[b * HH + i] = hh;
            hbf_t[b * HH + i] = f2bf(hh);
        }
    }
}

// ---------------- post-loop elementwise ----------------
__global__ void p1_add(float* __restrict__ y, const float* __restrict__ xe,
                       const float* __restrict__ b2_1, const float* __restrict__ bo_1) {
    int idx = blockIdx.x * 256 + threadIdx.x;
    int j = idx & (HH - 1);
    y[idx] += xe[idx] + b2_1[j] + bo_1[j];
}

__global__ void p2_cast(const float* __restrict__ y, u16* __restrict__ o) {
    int idx = blockIdx.x * 256 + threadIdx.x;
    o[idx] = f2bf(y[idx]);
}

// ---------------- host ----------------
extern "C" void kernel_launch(void* const* d_in, const int* in_sizes, int n_in,
                              void* d_out, int out_size, void* d_ws, size_t ws_size,
                              hipStream_t stream) {
    const int* x = (const int*)d_in[0];
    const float* emb = (const float*)d_in[1];
    const float* ln_g = (const float*)d_in[2];
    const float* ln_b = (const float*)d_in[3];
    const float* Wl = (const float*)d_in[4];
    const float* bl = (const float*)d_in[5];
    const float* Wo = (const float*)d_in[6];
    const float* bo = (const float*)d_in[7];
    const float* W1 = (const float*)d_in[8];
    const float* b1 = (const float*)d_in[9];
    const float* W2 = (const float*)d_in[10];
    const float* b2 = (const float*)d_in[11];
    float* out = (float*)d_out;

    char* wp = (char*)d_ws;
    auto alloc = [&](size_t bytes) { void* p = wp; wp += (bytes + 255) & ~(size_t)255; return p; };
    const size_t MBT = (size_t)TT * BB;  // 2048 rows
    float* xe     = (float*)alloc(MBT * HH * 4);
    float* pre_z0 = (float*)alloc(MBT * H4 * 4);
    float* ff0    = (float*)alloc(MBT * HH * 4);
    float* y0_all = (float*)alloc(MBT * HH * 4);
    u16* xn0      = (u16*)alloc(MBT * HH * 2);
    u16* xn1      = (u16*)alloc(MBT * HH * 2);
    u16* U0       = (u16*)alloc(MBT * H4 * 2);
    u16* U1       = (u16*)alloc(MBT * H4 * 2);
    u16* H1bf     = (u16*)alloc(MBT * HH * 2);
    u16* Y1bf     = (u16*)alloc(MBT * HH * 2);
    float* states = (float*)alloc(24576 * 4);
    float* h0buf = states;           // [2][4][1024]
    float* h1buf = states + 8192;    // [2][4][1024]
    float* c0 = states + 16384;      // [4][1024]
    float* c1 = states + 20480;      // [4][1024]
    u16* WlxT0 = (u16*)alloc((size_t)H4 * HH * 2);
    u16* WlhT0 = (u16*)alloc((size_t)H4 * HH * 2);
    u16* WlxT1 = (u16*)alloc((size_t)H4 * HH * 2);
    u16* WlhT1 = (u16*)alloc((size_t)H4 * HH * 2);
    u16* Wo0T  = (u16*)alloc((size_t)HH * HH * 2);
    u16* Wo1T  = (u16*)alloc((size_t)HH * HH * 2);
    u16* W10T  = (u16*)alloc((size_t)H4 * HH * 2);
    u16* W11T  = (u16*)alloc((size_t)H4 * HH * 2);
    u16* W20T  = (u16*)alloc((size_t)HH * H4 * 2);
    u16* W21T  = (u16*)alloc((size_t)HH * H4 * 2);
    u16* embB  = (u16*)alloc((size_t)VV * HH * 2);

    dim3 tb(32, 8);
    // Wl: [L][2H][4H]; rows 0..H-1 = x-part, H..2H-1 = h-part
    transpose_cast<<<dim3(128, 32), tb, 0, stream>>>(Wl, WlxT0, HH, H4);
    transpose_cast<<<dim3(128, 32), tb, 0, stream>>>(Wl + 1024 * 4096, WlhT0, HH, H4);
    transpose_cast<<<dim3(128, 32), tb, 0, stream>>>(Wl + 2048 * 4096, WlxT1, HH, H4);
    transpose_cast<<<dim3(128, 32), tb, 0, stream>>>(Wl + 3072 * 4096, WlhT1, HH, H4);
    transpose_cast<<<dim3(32, 32), tb, 0, stream>>>(Wo, Wo0T, HH, HH);
    transpose_cast<<<dim3(32, 32), tb, 0, stream>>>(Wo + 1024 * 1024, Wo1T, HH, HH);
    transpose_cast<<<dim3(128, 32), tb, 0, stream>>>(W1, W10T, HH, H4);
    transpose_cast<<<dim3(128, 32), tb, 0, stream>>>(W1 + 1024 * 4096, W11T, HH, H4);
    transpose_cast<<<dim3(32, 128), tb, 0, stream>>>(W2, W20T, H4, HH);
    transpose_cast<<<dim3(32, 128), tb, 0, stream>>>(W2 + 4096 * 1024, W21T, H4, HH);
    cast_bf16<<<(VV * HH + 255) / 256, 256, 0, stream>>>(emb, embB, VV * HH);
    gather_ln<<<dim3(TT, BB), 256, 0, stream>>>(x, emb, ln_g, ln_b, xe, xn0);

    // Phase A GEMMs
    gemm_bt<0><<<dim3(32, 16), 256, 0, stream>>>(xn0, WlxT0, pre_z0, nullptr, bl, 2048, 4096, 1024);
    gemm_bt<1><<<dim3(32, 16), 256, 0, stream>>>(xn0, W10T, nullptr, U0, b1, 2048, 4096, 1024);
    gemm_bt<0><<<dim3(8, 16), 256, 0, stream>>>(U0, W20T, ff0, nullptr, b2, 2048, 1024, 4096);

    zero_buf<<<96, 256, 0, stream>>>(states, 24576);

    // Phase B: sequential recurrence
    for (int t = 0; t < TT; t++) {
        const float* pz = pre_z0 + (size_t)t * BB * H4;
        float* h0_prev = h0buf + (t & 1) * 4096;
        float* h0_new = h0buf + ((t & 1) ^ 1) * 4096;
        float* h1_prev = h1buf + (t & 1) * 4096;
        float* h1_new = h1buf + ((t & 1) ^ 1) * 4096;
        size_t roff = (size_t)t * BB * HH;
        lstm0_step<<<256, 256, 0, stream>>>(WlhT0, pz, h0_prev, h0_new, c0);
        y0_step<<<256, 256, 0, stream>>>(Wo0T, h0_new, xe + roff, ff0 + roff, bo, y0_all + roff);
        ln_rows<<<4, 256, 0, stream>>>(y0_all + roff, ln_g + 1024, ln_b + 1024, xn1 + roff);
        lstm1_step<<<256, 256, 0, stream>>>(WlxT1, WlhT1, xn1 + roff, h1_prev, bl + 4096, c1, h1_new, H1bf + roff);
    }

    // Phase C: deferred layer-1 output + logits
    gemm_bt<1><<<dim3(32, 16), 256, 0, stream>>>(xn1, W11T, nullptr, U1, b1 + 4096, 2048, 4096, 1024);
    p1_add<<<8192, 256, 0, stream>>>(y0_all, xe, b2 + 1024, bo + 1024);
    gemm_bt<2><<<dim3(8, 16), 256, 0, stream>>>(U1, W21T, y0_all, nullptr, nullptr, 2048, 1024, 4096);
    gemm_bt<2><<<dim3(8, 16), 256, 0, stream>>>(H1bf, Wo1T, y0_all, nullptr, nullptr, 2048, 1024, 1024);
    p2_cast<<<8192, 256, 0, stream>>>(y0_all, Y1bf);
    gemm_bt<3><<<dim3(250, 16), 256, 0, stream>>>(Y1bf, embB, out, nullptr, nullptr, 2048, 32000, 1024);
}